// Round 1
// 836.844 us; speedup vs baseline: 1.2624x; 1.2624x over previous
//
#include <hip/hip_runtime.h>
#include <hip/hip_bf16.h>
#include <math.h>

typedef __bf16 bfx8 __attribute__((ext_vector_type(8)));
typedef __bf16 bfx4 __attribute__((ext_vector_type(4)));
typedef float f32x4 __attribute__((ext_vector_type(4)));

__device__ __forceinline__ int bitrev7(int x) {
  return ((x & 1) << 6) | ((x & 2) << 4) | ((x & 4) << 2) | (x & 8)
       | ((x & 16) >> 2) | ((x & 32) >> 4) | ((x & 64) >> 6);
}

// DIF radix-2 butterfly: a' = a+b ; b' = (a-b)*W, W = (tc, ts)
__device__ __forceinline__ void bfly(float& ar, float& ai, float& br, float& bi,
                                     float tc, float ts) {
  float dr = ar - br, di = ai - bi;
  ar += br; ai += bi;
  br = dr * tc - di * ts;
  bi = dr * ts + di * tc;
}

// 64-entry twiddle table: tw[k] = (cos(ang*k), sin(ang*k)), ang = sign*2pi/128
__device__ __forceinline__ void build_tw(float2* tw, float sign, int tid) {
  if (tid < 64) {
    float s_, c_;
    __sincosf(sign * (float)(2.0 * M_PI / 128.0) * (float)tid, &s_, &c_);
    tw[tid] = make_float2(c_, s_);
  }
}

// In-register DIF stages 0..4 of a 128-pt FFT.
// Thread holds points p = wq + 4a + 32b as x[b][a]; wq is wave-uniform ->
// all twiddle-table reads are LDS broadcasts (conflict-free).
__device__ __forceinline__ void fft_stages04(float (&xr)[4][8], float (&xi)[4][8],
                                             const float2* tw, int wq) {
  // stage 0: half=64, pairs (b, b+2), k = p
  #pragma unroll
  for (int a = 0; a < 8; ++a) {
    #pragma unroll
    for (int b = 0; b < 2; ++b) {
      float2 t = tw[wq + 4 * a + 32 * b];
      bfly(xr[b][a], xi[b][a], xr[b + 2][a], xi[b + 2][a], t.x, t.y);
    }
  }
  // stage 1: half=32, pairs (b, b+1) b in {0,2}, k = 2*(p mod 32) = 2*(wq+4a)
  #pragma unroll
  for (int a = 0; a < 8; ++a) {
    float2 t = tw[2 * (wq + 4 * a)];
    bfly(xr[0][a], xi[0][a], xr[1][a], xi[1][a], t.x, t.y);
    bfly(xr[2][a], xi[2][a], xr[3][a], xi[3][a], t.x, t.y);
  }
  // stage 2: half=16, pairs (a, a+4) a<4, k = 4*(wq+4a)
  #pragma unroll
  for (int a = 0; a < 4; ++a) {
    float2 t = tw[4 * (wq + 4 * a)];
    #pragma unroll
    for (int b = 0; b < 4; ++b)
      bfly(xr[b][a], xi[b][a], xr[b][a + 4], xi[b][a + 4], t.x, t.y);
  }
  // stage 3: half=8, pairs (a, a+2) a in {0,1,4,5}, k = 8*(wq + 4*(a&1))
  {
    float2 t0 = tw[8 * wq];
    float2 t1 = tw[8 * (wq + 4)];
    #pragma unroll
    for (int b = 0; b < 4; ++b) {
      bfly(xr[b][0], xi[b][0], xr[b][2], xi[b][2], t0.x, t0.y);
      bfly(xr[b][1], xi[b][1], xr[b][3], xi[b][3], t1.x, t1.y);
      bfly(xr[b][4], xi[b][4], xr[b][6], xi[b][6], t0.x, t0.y);
      bfly(xr[b][5], xi[b][5], xr[b][7], xi[b][7], t1.x, t1.y);
    }
  }
  // stage 4: half=4, pairs (a, a+1) a even, k = 16*wq
  {
    float2 t = tw[16 * wq];
    #pragma unroll
    for (int b = 0; b < 4; ++b) {
      #pragma unroll
      for (int a = 0; a < 8; a += 2)
        bfly(xr[b][a], xi[b][a], xr[b][a + 1], xi[b][a + 1], t.x, t.y);
    }
  }
}

// In-register DIF stages 5..6 on one contiguous quad (points 4g..4g+3).
// stage-5 twiddles are W^0 and W^32 = (0, sign); stage 6 twiddle-free.
__device__ __forceinline__ void fft_stages56(float (&yr)[4], float (&yi)[4], float sign) {
  float dr, di;
  dr = yr[0] - yr[2]; di = yi[0] - yi[2];
  yr[0] += yr[2]; yi[0] += yi[2]; yr[2] = dr; yi[2] = di;
  dr = yr[1] - yr[3]; di = yi[1] - yi[3];
  yr[1] += yr[3]; yi[1] += yi[3];
  yr[3] = -sign * di; yi[3] = sign * dr;
  dr = yr[0] - yr[1]; di = yi[0] - yi[1];
  yr[0] += yr[1]; yi[0] += yi[1]; yr[1] = dr; yi[1] = di;
  dr = yr[2] - yr[3]; di = yi[2] - yi[3];
  yr[2] += yr[3]; yi[2] += yi[3]; yr[3] = dr; yi[3] = di;
}

// ---- K1: forward rFFT along W (register FFT, 2 LDS passes).
__global__ __launch_bounds__(256, 2) void k_fftw_fwd(
    const float* __restrict__ x, float* __restrict__ Xr, float* __restrict__ Xi) {
  __shared__ float2 l[128 * 64];
  __shared__ float2 tw[64];
  const int bh = blockIdx.x;
  const int c0 = blockIdx.y * 64;
  const int tid = threadIdx.x;
  const int c = tid & 63, wq = tid >> 6;
  build_tw(tw, -1.f, tid);
  const float* xrow = x + (size_t)bh * (128 * 768) + c0 + c;
  float xr[4][8], xi_[4][8];
  #pragma unroll
  for (int b = 0; b < 4; ++b)
    #pragma unroll
    for (int a = 0; a < 8; ++a) {
      int p = wq + 4 * a + 32 * b;
      xr[b][a] = xrow[(size_t)p * 768];
      xi_[b][a] = 0.f;
    }
  __syncthreads();   // tw ready
  fft_stages04(xr, xi_, tw, wq);
  #pragma unroll
  for (int b = 0; b < 4; ++b)
    #pragma unroll
    for (int a = 0; a < 8; ++a) {
      int p = wq + 4 * a + 32 * b;
      l[p * 64 + c] = make_float2(xr[b][a], xi_[b][a]);
    }
  __syncthreads();
  const float sc = 1.f / 128.f;
  #pragma unroll
  for (int t = 0; t < 8; ++t) {
    int g = wq + 4 * t;
    float yr[4], yi[4];
    #pragma unroll
    for (int d = 0; d < 4; ++d) {
      float2 v = l[(4 * g + d) * 64 + c];
      yr[d] = v.x; yi[d] = v.y;
    }
    fft_stages56(yr, yi, -1.f);
    #pragma unroll
    for (int d = 0; d < 4; ++d) {
      int f = bitrev7(4 * g + d);
      if (f < 65) {
        Xr[((size_t)bh * 65 + f) * 768 + c0 + c]  = yr[d] * sc;
        Xi[((size_t)bh * 128 + f) * 768 + c0 + c] = yi[d] * sc;
      }
    }
  }
}

// ---- K2/K4: complex FFT along H, in-place per (b,wf) column.
__global__ __launch_bounds__(256, 2) void k_ffth(
    float* Xr, float* Xi, float sign, float scale) {
  __shared__ float2 l[128 * 64];
  __shared__ float2 tw[64];
  const int bw = blockIdx.x;
  const int b = bw / 65, wf = bw % 65;
  const int c0 = blockIdx.y * 64;
  const int tid = threadIdx.x;
  const int c = tid & 63, wq = tid >> 6;
  build_tw(tw, sign, tid);
  const size_t baser = ((size_t)b * 128 * 65 + wf) * 768 + c0 + c;
  const size_t basei = ((size_t)b * 128 * 128 + wf) * 768 + c0 + c;
  float xr[4][8], xi_[4][8];
  #pragma unroll
  for (int bb = 0; bb < 4; ++bb)
    #pragma unroll
    for (int a = 0; a < 8; ++a) {
      int p = wq + 4 * a + 32 * bb;
      xr[bb][a]  = Xr[baser + (size_t)p * (65 * 768)];
      xi_[bb][a] = Xi[basei + (size_t)p * (128 * 768)];
    }
  __syncthreads();
  fft_stages04(xr, xi_, tw, wq);
  #pragma unroll
  for (int bb = 0; bb < 4; ++bb)
    #pragma unroll
    for (int a = 0; a < 8; ++a) {
      int p = wq + 4 * a + 32 * bb;
      l[p * 64 + c] = make_float2(xr[bb][a], xi_[bb][a]);
    }
  __syncthreads();
  #pragma unroll
  for (int t = 0; t < 8; ++t) {
    int g = wq + 4 * t;
    float yr[4], yi[4];
    #pragma unroll
    for (int d = 0; d < 4; ++d) {
      float2 v = l[(4 * g + d) * 64 + c];
      yr[d] = v.x; yi[d] = v.y;
    }
    fft_stages56(yr, yi, sign);
    #pragma unroll
    for (int d = 0; d < 4; ++d) {
      int hf = bitrev7(4 * g + d);
      Xr[baser + (size_t)hf * (65 * 768)]  = yr[d] * scale;
      Xi[basei + (size_t)hf * (128 * 768)] = yi[d] * scale;
    }
  }
}

// ---- K3: block-diagonal complex MLP via bf16 MFMA. In-place on Xr/Xi.
// grid (520, 8): 64 positions x channel-block n per workgroup. 256 thr = 4 waves.
// Wave w computes rows [16w,16w+16) x all 96 out-channels (6 col tiles), r & i.
#define MP 104  // padded bf16 row length: 208 B rows (16B-aligned, 2-way banks = free)
__device__ __forceinline__ bfx8 neg8(bfx8 v) {
  union { bfx8 b; unsigned int u[4]; } t;
  t.b = v;
  t.u[0] ^= 0x80008000u; t.u[1] ^= 0x80008000u;
  t.u[2] ^= 0x80008000u; t.u[3] ^= 0x80008000u;
  return t.b;
}

__global__ __launch_bounds__(256, 2) void k_mlp(
    float* __restrict__ Xr, float* __restrict__ Xi,
    const float* __restrict__ w1, const float* __restrict__ b1,
    const float* __restrict__ w2, const float* __restrict__ b2) {
  __shared__ __align__(16) __bf16 Xl[2][64][MP];   // [r/i][m][k] activations (X, then O1)
  __shared__ __align__(16) __bf16 Wl[2][96][MP];   // [r/i][oc][k] weights (transposed)
  const int n = blockIdx.y;
  const int m0 = blockIdx.x * 64;
  const int tid = threadIdx.x;
  const int lane = tid & 63;
  const int w = tid >> 6;
  const int col = lane & 15;       // MFMA: A row / B col / C col
  const int quad = lane >> 4;      // MFMA: k-chunk / C row-group

  // stage X tile: fp32 global -> bf16 LDS [m][k]
  for (int e = tid; e < 64 * 24; e += 256) {
    int mm = e / 24, k4 = (e % 24) * 4;
    int m = m0 + mm;
    int bh = m / 65, wf = m - bh * 65;
    const float4 vr = *(const float4*)&Xr[(size_t)m * 768 + n * 96 + k4];
    const float4 vi = *(const float4*)&Xi[((size_t)bh * 128 + wf) * 768 + n * 96 + k4];
    bfx4 br = { (__bf16)vr.x, (__bf16)vr.y, (__bf16)vr.z, (__bf16)vr.w };
    bfx4 bi = { (__bf16)vi.x, (__bf16)vi.y, (__bf16)vi.z, (__bf16)vi.w };
    *(bfx4*)&Xl[0][mm][k4] = br;
    *(bfx4*)&Xl[1][mm][k4] = bi;
  }
  // stage W1: [k][oc] global -> [oc][k] LDS (bf16)
  for (int e = tid; e < 2 * 96 * 24; e += 256) {
    int ri = e / (96 * 24);
    int r = e - ri * (96 * 24);
    int kin = r / 24, oc4 = (r - kin * 24) * 4;
    const float4 v = *(const float4*)&w1[(size_t)ri * 73728 + ((size_t)n * 96 + kin) * 96 + oc4];
    Wl[ri][oc4 + 0][kin] = (__bf16)v.x;
    Wl[ri][oc4 + 1][kin] = (__bf16)v.y;
    Wl[ri][oc4 + 2][kin] = (__bf16)v.z;
    Wl[ri][oc4 + 3][kin] = (__bf16)v.w;
  }
  __syncthreads();

  const f32x4 fz = { 0.f, 0.f, 0.f, 0.f };
  f32x4 accR[6], accI[6];
  #pragma unroll
  for (int ct = 0; ct < 6; ++ct) { accR[ct] = fz; accI[ct] = fz; }

  // ============ layer 1 ============
  const int mrow = w * 16 + col;
  #pragma unroll
  for (int kc = 0; kc < 3; ++kc) {
    const int kb = kc * 32 + quad * 8;
    bfx8 axr = *(const bfx8*)&Xl[0][mrow][kb];
    bfx8 axi = *(const bfx8*)&Xl[1][mrow][kb];
    bfx8 axin = neg8(axi);
    #pragma unroll
    for (int ct = 0; ct < 6; ++ct) {
      bfx8 bwr = *(const bfx8*)&Wl[0][ct * 16 + col][kb];
      bfx8 bwi = *(const bfx8*)&Wl[1][ct * 16 + col][kb];
      accR[ct] = __builtin_amdgcn_mfma_f32_16x16x32_bf16(axr,  bwr, accR[ct], 0, 0, 0);
      accR[ct] = __builtin_amdgcn_mfma_f32_16x16x32_bf16(axin, bwi, accR[ct], 0, 0, 0);
      accI[ct] = __builtin_amdgcn_mfma_f32_16x16x32_bf16(axi,  bwr, accI[ct], 0, 0, 0);
      accI[ct] = __builtin_amdgcn_mfma_f32_16x16x32_bf16(axr,  bwi, accI[ct], 0, 0, 0);
    }
  }
  __syncthreads();   // all waves done reading Xl/Wl for layer 1

  // epilogue 1: bias + exact GELU -> bf16 O1 into Xl; stage W2 into Wl
  #pragma unroll
  for (int ct = 0; ct < 6; ++ct) {
    int oc = ct * 16 + col;
    float br = b1[n * 96 + oc];
    float bi = b1[768 + n * 96 + oc];
    int mbase = w * 16 + quad * 4;
    #pragma unroll
    for (int r = 0; r < 4; ++r) {
      float vr = accR[ct][r] + br;
      float vi = accI[ct][r] + bi;
      vr = 0.5f * vr * (1.f + erff(vr * 0.70710678118654752f));
      vi = 0.5f * vi * (1.f + erff(vi * 0.70710678118654752f));
      Xl[0][mbase + r][oc] = (__bf16)vr;
      Xl[1][mbase + r][oc] = (__bf16)vi;
    }
  }
  for (int e = tid; e < 2 * 96 * 24; e += 256) {
    int ri = e / (96 * 24);
    int r = e - ri * (96 * 24);
    int kin = r / 24, oc4 = (r - kin * 24) * 4;
    const float4 v = *(const float4*)&w2[(size_t)ri * 73728 + ((size_t)n * 96 + kin) * 96 + oc4];
    Wl[ri][oc4 + 0][kin] = (__bf16)v.x;
    Wl[ri][oc4 + 1][kin] = (__bf16)v.y;
    Wl[ri][oc4 + 2][kin] = (__bf16)v.z;
    Wl[ri][oc4 + 3][kin] = (__bf16)v.w;
  }
  __syncthreads();

  // ============ layer 2 ============
  #pragma unroll
  for (int ct = 0; ct < 6; ++ct) { accR[ct] = fz; accI[ct] = fz; }
  #pragma unroll
  for (int kc = 0; kc < 3; ++kc) {
    const int kb = kc * 32 + quad * 8;
    bfx8 axr = *(const bfx8*)&Xl[0][mrow][kb];
    bfx8 axi = *(const bfx8*)&Xl[1][mrow][kb];
    bfx8 axin = neg8(axi);
    #pragma unroll
    for (int ct = 0; ct < 6; ++ct) {
      bfx8 bwr = *(const bfx8*)&Wl[0][ct * 16 + col][kb];
      bfx8 bwi = *(const bfx8*)&Wl[1][ct * 16 + col][kb];
      accR[ct] = __builtin_amdgcn_mfma_f32_16x16x32_bf16(axr,  bwr, accR[ct], 0, 0, 0);
      accR[ct] = __builtin_amdgcn_mfma_f32_16x16x32_bf16(axin, bwi, accR[ct], 0, 0, 0);
      accI[ct] = __builtin_amdgcn_mfma_f32_16x16x32_bf16(axi,  bwr, accI[ct], 0, 0, 0);
      accI[ct] = __builtin_amdgcn_mfma_f32_16x16x32_bf16(axr,  bwi, accI[ct], 0, 0, 0);
    }
  }

  // epilogue 2: bias + softshrink, fp32 store to global (in-place)
  #pragma unroll
  for (int ct = 0; ct < 6; ++ct) {
    int oc = ct * 16 + col;
    float br = b2[n * 96 + oc];
    float bi = b2[768 + n * 96 + oc];
    #pragma unroll
    for (int r = 0; r < 4; ++r) {
      int m = m0 + w * 16 + quad * 4 + r;
      int bh = m / 65, wf = m - bh * 65;
      float vr = accR[ct][r] + br;
      float vi = accI[ct][r] + bi;
      vr = (vr > 0.01f) ? vr - 0.01f : ((vr < -0.01f) ? vr + 0.01f : 0.f);
      vi = (vi > 0.01f) ? vi - 0.01f : ((vi < -0.01f) ? vi + 0.01f : 0.f);
      Xr[(size_t)m * 768 + n * 96 + oc] = vr;
      Xi[((size_t)bh * 128 + wf) * 768 + n * 96 + oc] = vi;
    }
  }
}

// ---- K5: inverse rFFT along W (hermitian extension via mirrored global reads).
__global__ __launch_bounds__(256, 2) void k_ifftw(
    const float* __restrict__ Xr, float* io) {
  __shared__ float2 l[128 * 64];
  __shared__ float2 tw[64];
  const int bh = blockIdx.x;
  const int c0 = blockIdx.y * 64;
  const int tid = threadIdx.x;
  const int c = tid & 63, wq = tid >> 6;
  build_tw(tw, +1.f, tid);
  float xr[4][8], xi_[4][8];
  #pragma unroll
  for (int b = 0; b < 4; ++b)
    #pragma unroll
    for (int a = 0; a < 8; ++a) {
      int p = wq + 4 * a + 32 * b;
      int src = (p <= 64) ? p : 128 - p;
      float sg = (p <= 64) ? 1.f : -1.f;   // conjugate for hermitian extension
      xr[b][a]  = Xr[((size_t)bh * 65 + src) * 768 + c0 + c];
      xi_[b][a] = sg * io[((size_t)bh * 128 + src) * 768 + c0 + c];
    }
  __syncthreads();
  fft_stages04(xr, xi_, tw, wq);
  #pragma unroll
  for (int b = 0; b < 4; ++b)
    #pragma unroll
    for (int a = 0; a < 8; ++a) {
      int p = wq + 4 * a + 32 * b;
      l[p * 64 + c] = make_float2(xr[b][a], xi_[b][a]);
    }
  __syncthreads();
  #pragma unroll
  for (int t = 0; t < 8; ++t) {
    int g = wq + 4 * t;
    float yr[4], yi[4];
    #pragma unroll
    for (int d = 0; d < 4; ++d) {
      float2 v = l[(4 * g + d) * 64 + c];
      yr[d] = v.x; yi[d] = v.y;
    }
    fft_stages56(yr, yi, +1.f);
    #pragma unroll
    for (int d = 0; d < 4; ++d) {
      int w = bitrev7(4 * g + d);
      io[((size_t)bh * 128 + w) * 768 + c0 + c] = yr[d];
    }
  }
}

extern "C" void kernel_launch(void* const* d_in, const int* in_sizes, int n_in,
                              void* d_out, int out_size, void* d_ws, size_t ws_size,
                              hipStream_t stream) {
  const float* x  = (const float*)d_in[0];
  const float* w1 = (const float*)d_in[1];
  const float* b1 = (const float*)d_in[2];
  const float* w2 = (const float*)d_in[3];
  const float* b2 = (const float*)d_in[4];
  float* out = (float*)d_out;
  float* Xr = (float*)d_ws;   // [512, 65, 768] fp32 (real spectrum)
  float* Xi = out;            // padded [512, 128, 768], wf slots 0..64 (imag spectrum)

  dim3 blk(256);
  k_fftw_fwd<<<dim3(512, 12), blk, 0, stream>>>(x, Xr, Xi);
  k_ffth   <<<dim3(260, 12), blk, 0, stream>>>(Xr, Xi, -1.f, 1.f);
  k_mlp    <<<dim3(520, 8),  blk, 0, stream>>>(Xr, Xi, w1, b1, w2, b2);
  k_ffth   <<<dim3(260, 12), blk, 0, stream>>>(Xr, Xi, +1.f, 1.f / 128.f);
  k_ifftw  <<<dim3(512, 12), blk, 0, stream>>>(Xr, out);
}

// Round 2
// 750.384 us; speedup vs baseline: 1.4079x; 1.1152x over previous
//
#include <hip/hip_runtime.h>
#include <hip/hip_bf16.h>
#include <math.h>

typedef __bf16 bfx8 __attribute__((ext_vector_type(8)));
typedef __bf16 bfx4 __attribute__((ext_vector_type(4)));
typedef float f32x4 __attribute__((ext_vector_type(4)));

__device__ __forceinline__ int bitrev7(int x) {
  return ((x & 1) << 6) | ((x & 2) << 4) | ((x & 4) << 2) | (x & 8)
       | ((x & 16) >> 2) | ((x & 32) >> 4) | ((x & 64) >> 6);
}

// DIF radix-2 butterfly: a' = a+b ; b' = (a-b)*W, W = (tc, ts)
__device__ __forceinline__ void bfly(float& ar, float& ai, float& br, float& bi,
                                     float tc, float ts) {
  float dr = ar - br, di = ai - bi;
  ar += br; ai += bi;
  br = dr * tc - di * ts;
  bi = dr * ts + di * tc;
}

__device__ __forceinline__ void build_tw(float2* tw, float sign, int tid) {
  if (tid < 64) {
    float s_, c_;
    __sincosf(sign * (float)(2.0 * M_PI / 128.0) * (float)tid, &s_, &c_);
    tw[tid] = make_float2(c_, s_);
  }
}

// In-register DIF stages 0..4 of a 128-pt FFT. Thread holds p = wq + 4a + 32b.
__device__ __forceinline__ void fft_stages04(float (&xr)[4][8], float (&xi)[4][8],
                                             const float2* tw, int wq) {
  #pragma unroll
  for (int a = 0; a < 8; ++a) {
    #pragma unroll
    for (int b = 0; b < 2; ++b) {
      float2 t = tw[wq + 4 * a + 32 * b];
      bfly(xr[b][a], xi[b][a], xr[b + 2][a], xi[b + 2][a], t.x, t.y);
    }
  }
  #pragma unroll
  for (int a = 0; a < 8; ++a) {
    float2 t = tw[2 * (wq + 4 * a)];
    bfly(xr[0][a], xi[0][a], xr[1][a], xi[1][a], t.x, t.y);
    bfly(xr[2][a], xi[2][a], xr[3][a], xi[3][a], t.x, t.y);
  }
  #pragma unroll
  for (int a = 0; a < 4; ++a) {
    float2 t = tw[4 * (wq + 4 * a)];
    #pragma unroll
    for (int b = 0; b < 4; ++b)
      bfly(xr[b][a], xi[b][a], xr[b][a + 4], xi[b][a + 4], t.x, t.y);
  }
  {
    float2 t0 = tw[8 * wq];
    float2 t1 = tw[8 * (wq + 4)];
    #pragma unroll
    for (int b = 0; b < 4; ++b) {
      bfly(xr[b][0], xi[b][0], xr[b][2], xi[b][2], t0.x, t0.y);
      bfly(xr[b][1], xi[b][1], xr[b][3], xi[b][3], t1.x, t1.y);
      bfly(xr[b][4], xi[b][4], xr[b][6], xi[b][6], t0.x, t0.y);
      bfly(xr[b][5], xi[b][5], xr[b][7], xi[b][7], t1.x, t1.y);
    }
  }
  {
    float2 t = tw[16 * wq];
    #pragma unroll
    for (int b = 0; b < 4; ++b) {
      #pragma unroll
      for (int a = 0; a < 8; a += 2)
        bfly(xr[b][a], xi[b][a], xr[b][a + 1], xi[b][a + 1], t.x, t.y);
    }
  }
}

// Stages 5..6 on one contiguous quad; stage-5 twiddles are W^0 and +-i.
__device__ __forceinline__ void fft_stages56(float (&yr)[4], float (&yi)[4], float sign) {
  float dr, di;
  dr = yr[0] - yr[2]; di = yi[0] - yi[2];
  yr[0] += yr[2]; yi[0] += yi[2]; yr[2] = dr; yi[2] = di;
  dr = yr[1] - yr[3]; di = yi[1] - yi[3];
  yr[1] += yr[3]; yi[1] += yi[3];
  yr[3] = -sign * di; yi[3] = sign * dr;
  dr = yr[0] - yr[1]; di = yi[0] - yi[1];
  yr[0] += yr[1]; yi[0] += yi[1]; yr[1] = dr; yi[1] = di;
  dr = yr[2] - yr[3]; di = yi[2] - yi[3];
  yr[2] += yr[3]; yi[2] += yi[3]; yr[3] = dr; yi[3] = di;
}

// ---- K1: forward rFFT along W.
__global__ __launch_bounds__(256, 2) void k_fftw_fwd(
    const float* __restrict__ x, float* __restrict__ Xr, float* __restrict__ Xi) {
  __shared__ float2 l[128 * 64];
  __shared__ float2 tw[64];
  const int bh = blockIdx.x;
  const int c0 = blockIdx.y * 64;
  const int tid = threadIdx.x;
  const int c = tid & 63, wq = tid >> 6;
  build_tw(tw, -1.f, tid);
  const float* xrow = x + (size_t)bh * (128 * 768) + c0 + c;
  float xr[4][8], xi_[4][8];
  #pragma unroll
  for (int b = 0; b < 4; ++b)
    #pragma unroll
    for (int a = 0; a < 8; ++a) {
      int p = wq + 4 * a + 32 * b;
      xr[b][a] = xrow[(size_t)p * 768];
      xi_[b][a] = 0.f;
    }
  __syncthreads();
  fft_stages04(xr, xi_, tw, wq);
  #pragma unroll
  for (int b = 0; b < 4; ++b)
    #pragma unroll
    for (int a = 0; a < 8; ++a) {
      int p = wq + 4 * a + 32 * b;
      l[p * 64 + c] = make_float2(xr[b][a], xi_[b][a]);
    }
  __syncthreads();
  const float sc = 1.f / 128.f;
  #pragma unroll
  for (int t = 0; t < 8; ++t) {
    int g = wq + 4 * t;
    float yr[4], yi[4];
    #pragma unroll
    for (int d = 0; d < 4; ++d) {
      float2 v = l[(4 * g + d) * 64 + c];
      yr[d] = v.x; yi[d] = v.y;
    }
    fft_stages56(yr, yi, -1.f);
    #pragma unroll
    for (int d = 0; d < 4; ++d) {
      int f = bitrev7(4 * g + d);
      if (f < 65) {
        Xr[((size_t)bh * 65 + f) * 768 + c0 + c]  = yr[d] * sc;
        Xi[((size_t)bh * 128 + f) * 768 + c0 + c] = yi[d] * sc;
      }
    }
  }
}

// ---- K2/K4: complex FFT along H.
__global__ __launch_bounds__(256, 2) void k_ffth(
    float* Xr, float* Xi, float sign, float scale) {
  __shared__ float2 l[128 * 64];
  __shared__ float2 tw[64];
  const int bw = blockIdx.x;
  const int b = bw / 65, wf = bw % 65;
  const int c0 = blockIdx.y * 64;
  const int tid = threadIdx.x;
  const int c = tid & 63, wq = tid >> 6;
  build_tw(tw, sign, tid);
  const size_t baser = ((size_t)b * 128 * 65 + wf) * 768 + c0 + c;
  const size_t basei = ((size_t)b * 128 * 128 + wf) * 768 + c0 + c;
  float xr[4][8], xi_[4][8];
  #pragma unroll
  for (int bb = 0; bb < 4; ++bb)
    #pragma unroll
    for (int a = 0; a < 8; ++a) {
      int p = wq + 4 * a + 32 * bb;
      xr[bb][a]  = Xr[baser + (size_t)p * (65 * 768)];
      xi_[bb][a] = Xi[basei + (size_t)p * (128 * 768)];
    }
  __syncthreads();
  fft_stages04(xr, xi_, tw, wq);
  #pragma unroll
  for (int bb = 0; bb < 4; ++bb)
    #pragma unroll
    for (int a = 0; a < 8; ++a) {
      int p = wq + 4 * a + 32 * bb;
      l[p * 64 + c] = make_float2(xr[bb][a], xi_[bb][a]);
    }
  __syncthreads();
  #pragma unroll
  for (int t = 0; t < 8; ++t) {
    int g = wq + 4 * t;
    float yr[4], yi[4];
    #pragma unroll
    for (int d = 0; d < 4; ++d) {
      float2 v = l[(4 * g + d) * 64 + c];
      yr[d] = v.x; yi[d] = v.y;
    }
    fft_stages56(yr, yi, sign);
    #pragma unroll
    for (int d = 0; d < 4; ++d) {
      int hf = bitrev7(4 * g + d);
      Xr[baser + (size_t)hf * (65 * 768)]  = yr[d] * scale;
      Xi[basei + (size_t)hf * (128 * 768)] = yi[d] * scale;
    }
  }
}

// ---- K0: one-time weight transpose+cast: w[L][ri][n][kin][oc] f32
// -> wt_q[n][oc][kin] bf16, q = L*2+ri, stored in out's unused Xi rows
// (bh = q, wf = 65..112; overwritten only by the final k_ifftw).
__global__ void k_wprep(const float* __restrict__ w1, const float* __restrict__ w2,
                        float* __restrict__ out) {
  int e = blockIdx.x * 256 + threadIdx.x;   // 36864 items
  int kin8 = e % 12;
  int t = e / 12;
  int oc = t % 96;
  int t2 = t / 96;            // 0..31
  int n = t2 & 7;
  int q = t2 >> 3;            // 0..3 = (L, ri)
  int L = q >> 1, ri = q & 1;
  const float* src = (L ? w2 : w1) + (size_t)ri * 73728 + ((size_t)n * 96) * 96 + oc;
  bfx8 v;
  #pragma unroll
  for (int j = 0; j < 8; ++j)
    v[j] = (__bf16)src[(size_t)(kin8 * 8 + j) * 96];
  __bf16* wt = (__bf16*)(out + ((size_t)q * 128 + 65) * 768);
  *(bfx8*)&wt[((size_t)(n * 96 + oc)) * 96 + kin8 * 8] = v;
}

// ---- K3: block-diagonal complex MLP via bf16 MFMA, barrier-free.
// grid (520, 8), 256 thr = 4 waves; wave w owns rows [16w,16w+16).
// A-frags load direct from global (fp32->bf16 in reg); B-frags load direct
// from pre-transposed bf16 weights (L1/L2-resident). LDS holds only the
// wave-private O1 buffer, XOR-swizzled for conflict-free access.
#define MPB 208   // O1 row pitch in bytes (13 x 16B blocks)
__device__ __forceinline__ bfx8 neg8(bfx8 v) {
  union { bfx8 b; unsigned int u[4]; } t;
  t.b = v;
  t.u[0] ^= 0x80008000u; t.u[1] ^= 0x80008000u;
  t.u[2] ^= 0x80008000u; t.u[3] ^= 0x80008000u;
  return t.b;
}

__global__ __launch_bounds__(256, 4) void k_mlp(
    float* __restrict__ Xr, float* __restrict__ Xi,
    const __bf16* __restrict__ wt0,
    const float* __restrict__ b1, const float* __restrict__ b2) {
  // swizzle: bytecol ^= ((row>>2)&3)<<4 — bijective within the 208-B row,
  // spreads the 4 quads across distinct bank groups for writes AND b128 reads.
  __shared__ __align__(16) unsigned char O1[2 * 64 * MPB];   // 26624 B

  const int n = blockIdx.y;
  const int m0 = blockIdx.x * 64;
  const int tid = threadIdx.x;
  const int lane = tid & 63;
  const int w = tid >> 6;
  const int col = lane & 15;
  const int quad = lane >> 4;
  const int mrow = w * 16 + col;
  const int m = m0 + mrow;
  const int bh = m / 65, wf = m - bh * 65;
  const size_t xr_base = (size_t)m * 768 + n * 96;
  const size_t xi_base = ((size_t)bh * 128 + wf) * 768 + n * 96;
  const __bf16* w1r = wt0 + (size_t)n * 9216;
  const __bf16* w1i = w1r + 196608;
  const __bf16* w2r = w1r + 2 * 196608;
  const __bf16* w2i = w1r + 3 * 196608;

  const f32x4 fz = { 0.f, 0.f, 0.f, 0.f };
  f32x4 accR[6], accI[6];
  #pragma unroll
  for (int ct = 0; ct < 6; ++ct) { accR[ct] = fz; accI[ct] = fz; }

  // ============ layer 1: A from global X, B from global wt ============
  #pragma unroll
  for (int kc = 0; kc < 3; ++kc) {
    const int kb = kc * 32 + quad * 8;
    float4 vr0 = *(const float4*)&Xr[xr_base + kb];
    float4 vr1 = *(const float4*)&Xr[xr_base + kb + 4];
    float4 vi0 = *(const float4*)&Xi[xi_base + kb];
    float4 vi1 = *(const float4*)&Xi[xi_base + kb + 4];
    bfx8 axr = { (__bf16)vr0.x, (__bf16)vr0.y, (__bf16)vr0.z, (__bf16)vr0.w,
                 (__bf16)vr1.x, (__bf16)vr1.y, (__bf16)vr1.z, (__bf16)vr1.w };
    bfx8 axi = { (__bf16)vi0.x, (__bf16)vi0.y, (__bf16)vi0.z, (__bf16)vi0.w,
                 (__bf16)vi1.x, (__bf16)vi1.y, (__bf16)vi1.z, (__bf16)vi1.w };
    bfx8 axin = neg8(axi);
    #pragma unroll
    for (int ct = 0; ct < 6; ++ct) {
      const size_t wb = (size_t)(ct * 16 + col) * 96 + kb;
      bfx8 bwr = *(const bfx8*)&w1r[wb];
      bfx8 bwi = *(const bfx8*)&w1i[wb];
      accR[ct] = __builtin_amdgcn_mfma_f32_16x16x32_bf16(axr,  bwr, accR[ct], 0, 0, 0);
      accR[ct] = __builtin_amdgcn_mfma_f32_16x16x32_bf16(axin, bwi, accR[ct], 0, 0, 0);
      accI[ct] = __builtin_amdgcn_mfma_f32_16x16x32_bf16(axi,  bwr, accI[ct], 0, 0, 0);
      accI[ct] = __builtin_amdgcn_mfma_f32_16x16x32_bf16(axr,  bwi, accI[ct], 0, 0, 0);
    }
  }

  // epilogue 1: bias + exact GELU -> bf16 O1 (wave-private rows, no barrier)
  #pragma unroll
  for (int ct = 0; ct < 6; ++ct) {
    int oc = ct * 16 + col;
    float br = b1[n * 96 + oc];
    float bi = b1[768 + n * 96 + oc];
    #pragma unroll
    for (int r = 0; r < 4; ++r) {
      int row = w * 16 + quad * 4 + r;
      float vr = accR[ct][r] + br;
      float vi = accI[ct][r] + bi;
      vr = 0.5f * vr * (1.f + erff(vr * 0.70710678118654752f));
      vi = 0.5f * vi * (1.f + erff(vi * 0.70710678118654752f));
      int mask = ((row >> 2) & 3) << 4;
      *(__bf16*)&O1[row * MPB + ((oc * 2) ^ mask)]             = (__bf16)vr;
      *(__bf16*)&O1[64 * MPB + row * MPB + ((oc * 2) ^ mask)]  = (__bf16)vi;
    }
  }
  // intra-wave fence: O1 writes visible before layer-2 reads (no cross-wave use)
  asm volatile("s_waitcnt lgkmcnt(0)" ::: "memory");

  // ============ layer 2: A from O1 (LDS), B from global wt ============
  #pragma unroll
  for (int ct = 0; ct < 6; ++ct) { accR[ct] = fz; accI[ct] = fz; }
  const int amask = ((mrow >> 2) & 3) << 4;
  #pragma unroll
  for (int kc = 0; kc < 3; ++kc) {
    const int kb = kc * 32 + quad * 8;
    const int bc = (kb * 2) ^ amask;      // 16B-aligned, XOR bits 4..5
    bfx8 axr = *(const bfx8*)&O1[mrow * MPB + bc];
    bfx8 axi = *(const bfx8*)&O1[64 * MPB + mrow * MPB + bc];
    bfx8 axin = neg8(axi);
    #pragma unroll
    for (int ct = 0; ct < 6; ++ct) {
      const size_t wb = (size_t)(ct * 16 + col) * 96 + kb;
      bfx8 bwr = *(const bfx8*)&w2r[wb];
      bfx8 bwi = *(const bfx8*)&w2i[wb];
      accR[ct] = __builtin_amdgcn_mfma_f32_16x16x32_bf16(axr,  bwr, accR[ct], 0, 0, 0);
      accR[ct] = __builtin_amdgcn_mfma_f32_16x16x32_bf16(axin, bwi, accR[ct], 0, 0, 0);
      accI[ct] = __builtin_amdgcn_mfma_f32_16x16x32_bf16(axi,  bwr, accI[ct], 0, 0, 0);
      accI[ct] = __builtin_amdgcn_mfma_f32_16x16x32_bf16(axr,  bwi, accI[ct], 0, 0, 0);
    }
  }

  // epilogue 2: bias + softshrink, fp32 store to global (in-place)
  #pragma unroll
  for (int ct = 0; ct < 6; ++ct) {
    int oc = ct * 16 + col;
    float br = b2[n * 96 + oc];
    float bi = b2[768 + n * 96 + oc];
    #pragma unroll
    for (int r = 0; r < 4; ++r) {
      int mm = m0 + w * 16 + quad * 4 + r;
      int bh2 = mm / 65, wf2 = mm - bh2 * 65;
      float vr = accR[ct][r] + br;
      float vi = accI[ct][r] + bi;
      vr = (vr > 0.01f) ? vr - 0.01f : ((vr < -0.01f) ? vr + 0.01f : 0.f);
      vi = (vi > 0.01f) ? vi - 0.01f : ((vi < -0.01f) ? vi + 0.01f : 0.f);
      Xr[(size_t)mm * 768 + n * 96 + oc] = vr;
      Xi[((size_t)bh2 * 128 + wf2) * 768 + n * 96 + oc] = vi;
    }
  }
}

// ---- K5: inverse rFFT along W (hermitian extension via mirrored global reads).
__global__ __launch_bounds__(256, 2) void k_ifftw(
    const float* __restrict__ Xr, float* io) {
  __shared__ float2 l[128 * 64];
  __shared__ float2 tw[64];
  const int bh = blockIdx.x;
  const int c0 = blockIdx.y * 64;
  const int tid = threadIdx.x;
  const int c = tid & 63, wq = tid >> 6;
  build_tw(tw, +1.f, tid);
  float xr[4][8], xi_[4][8];
  #pragma unroll
  for (int b = 0; b < 4; ++b)
    #pragma unroll
    for (int a = 0; a < 8; ++a) {
      int p = wq + 4 * a + 32 * b;
      int src = (p <= 64) ? p : 128 - p;
      float sg = (p <= 64) ? 1.f : -1.f;
      xr[b][a]  = Xr[((size_t)bh * 65 + src) * 768 + c0 + c];
      xi_[b][a] = sg * io[((size_t)bh * 128 + src) * 768 + c0 + c];
    }
  __syncthreads();
  fft_stages04(xr, xi_, tw, wq);
  #pragma unroll
  for (int b = 0; b < 4; ++b)
    #pragma unroll
    for (int a = 0; a < 8; ++a) {
      int p = wq + 4 * a + 32 * b;
      l[p * 64 + c] = make_float2(xr[b][a], xi_[b][a]);
    }
  __syncthreads();
  #pragma unroll
  for (int t = 0; t < 8; ++t) {
    int g = wq + 4 * t;
    float yr[4], yi[4];
    #pragma unroll
    for (int d = 0; d < 4; ++d) {
      float2 v = l[(4 * g + d) * 64 + c];
      yr[d] = v.x; yi[d] = v.y;
    }
    fft_stages56(yr, yi, +1.f);
    #pragma unroll
    for (int d = 0; d < 4; ++d) {
      int w = bitrev7(4 * g + d);
      io[((size_t)bh * 128 + w) * 768 + c0 + c] = yr[d];
    }
  }
}

extern "C" void kernel_launch(void* const* d_in, const int* in_sizes, int n_in,
                              void* d_out, int out_size, void* d_ws, size_t ws_size,
                              hipStream_t stream) {
  const float* x  = (const float*)d_in[0];
  const float* w1 = (const float*)d_in[1];
  const float* b1 = (const float*)d_in[2];
  const float* w2 = (const float*)d_in[3];
  const float* b2 = (const float*)d_in[4];
  float* out = (float*)d_out;
  float* Xr = (float*)d_ws;   // [512, 65, 768] fp32 (real spectrum)
  float* Xi = out;            // padded [512, 128, 768], wf slots 0..64 (imag spectrum)
  const __bf16* wt0 = (const __bf16*)(out + (size_t)65 * 768);  // wf=65.. rows, bh 0..3

  dim3 blk(256);
  k_wprep  <<<dim3(144),      blk, 0, stream>>>(w1, w2, out);
  k_fftw_fwd<<<dim3(512, 12), blk, 0, stream>>>(x, Xr, Xi);
  k_ffth   <<<dim3(260, 12),  blk, 0, stream>>>(Xr, Xi, -1.f, 1.f);
  k_mlp    <<<dim3(520, 8),   blk, 0, stream>>>(Xr, Xi, wt0, b1, b2);
  k_ffth   <<<dim3(260, 12),  blk, 0, stream>>>(Xr, Xi, +1.f, 1.f / 128.f);
  k_ifftw  <<<dim3(512, 12),  blk, 0, stream>>>(Xr, out);
}